// Round 1
// baseline (18611.267 us; speedup 1.0000x reference)
//
#include <hip/hip_runtime.h>
#include <math.h>

#define BB 64
#define TT 256
#define VV 2000
#define EE 256
#define HD 256
#define ENC 256
#define AA 256
#define PP 512   // HI*WI = 16*32

// ---------------- precompute kernels ----------------

// mean over pixels: mean[b][c]
__global__ void k_mean(const float* __restrict__ enc, float* __restrict__ meanb) {
    int b = blockIdx.x, c = threadIdx.x;
    const float4* p4 = reinterpret_cast<const float4*>(enc + ((size_t)b*ENC + c)*PP);
    float s = 0.f;
    for (int i = 0; i < PP/4; ++i) { float4 v = p4[i]; s += v.x + v.y + v.z + v.w; }
    meanb[b*ENC + c] = s * (1.0f/PP);
}

// h0 = tanh(mean@W_inith^T + b), c0 likewise; layer1 initialized to same values
__global__ void k_init(const float* __restrict__ meanb,
                       const float* __restrict__ Winith, const float* __restrict__ binith,
                       const float* __restrict__ Winitc, const float* __restrict__ binitc,
                       float* __restrict__ h0, float* __restrict__ c0,
                       float* __restrict__ h1i, float* __restrict__ c1) {
    __shared__ float ms[ENC];
    int b = blockIdx.x, j = threadIdx.x;
    ms[j] = meanb[b*ENC + j];
    __syncthreads();
    float ah = binith[j], ac = binitc[j];
    const float4* wh = (const float4*)(Winith + (size_t)j*ENC);
    const float4* wc = (const float4*)(Winitc + (size_t)j*ENC);
    const float4* m4 = (const float4*)ms;
    for (int k = 0; k < ENC/4; ++k) {
        float4 m = m4[k], a = wh[k], b2 = wc[k];
        ah += a.x*m.x + a.y*m.y + a.z*m.z + a.w*m.w;
        ac += b2.x*m.x + b2.y*m.y + b2.z*m.z + b2.w*m.w;
    }
    float hv = tanhf(ah), cv = tanhf(ac);
    h0[b*HD + j] = hv; c0[b*HD + j] = cv;
    h1i[b*HD + j] = hv; c1[b*HD + j] = cv;
}

// att1T[b][a][p] = sum_c enc[b][c][p] * W_ae[a][c] + b_ae[a]
__global__ void k_att1T(const float* __restrict__ enc, const float* __restrict__ Wae,
                        const float* __restrict__ bae, float* __restrict__ att1T) {
    __shared__ float wsm[16][ENC];
    int a0 = blockIdx.x * 16, b = blockIdx.y, p = threadIdx.x;
    for (int i = threadIdx.x; i < 16*ENC; i += 512) wsm[i >> 8][i & 255] = Wae[(size_t)a0*ENC + i];
    __syncthreads();
    float acc[16];
    #pragma unroll
    for (int i = 0; i < 16; ++i) acc[i] = 0.f;
    const float* eb = enc + (size_t)b*ENC*PP + p;
    for (int c = 0; c < ENC; ++c) {
        float v = eb[(size_t)c*PP];
        #pragma unroll
        for (int i = 0; i < 16; ++i) acc[i] += v * wsm[i][c];
    }
    for (int i = 0; i < 16; ++i)
        att1T[((size_t)b*AA + a0 + i)*PP + p] = acc[i] + bae[a0 + i];
}

// ---------------- per-step kernels ----------------

// att2[b][a] = h1[b]@W_ad[a]^T + b_ad[a]
__global__ void s0_att2(const float* __restrict__ h1, const float* __restrict__ Wad,
                        const float* __restrict__ bad, float* __restrict__ att2g) {
    __shared__ float h1t[16][HD];
    int a0 = blockIdx.x * 32, b0 = blockIdx.y * 16, tid = threadIdx.x;
    for (int i = tid; i < 16*HD; i += 256) h1t[i >> 8][i & 255] = h1[(b0 + (i >> 8))*HD + (i & 255)];
    __syncthreads();
    int a_l = tid & 31, b_l = tid >> 5;
    int a = a0 + a_l;
    const float4* wr = (const float4*)(Wad + (size_t)a*HD);
    const float4* x0 = (const float4*)h1t[b_l];
    const float4* x1 = (const float4*)h1t[b_l + 8];
    float acc0 = 0.f, acc1 = 0.f;
    for (int k = 0; k < HD/4; ++k) {
        float4 w = wr[k], p = x0[k], q = x1[k];
        acc0 += w.x*p.x + w.y*p.y + w.z*p.z + w.w*p.w;
        acc1 += w.x*q.x + w.y*q.y + w.z*q.z + w.w*q.w;
    }
    float bb2 = bad[a];
    att2g[(b0 + b_l)*AA + a]     = acc0 + bb2;
    att2g[(b0 + b_l + 8)*AA + a] = acc1 + bb2;
}

// score/softmax(unnormalized)/partial-ctx for p-chunk of 128
__global__ void s1_score(const float* __restrict__ att1T, const float* __restrict__ encf,
                         const float* __restrict__ att2g, const float* __restrict__ wfa,
                         const float* __restrict__ bfa, float* __restrict__ ws_e,
                         float* __restrict__ ctxU, float* __restrict__ Zpart, int t) {
    __shared__ float a2[AA], wf[AA], ps[2][128], es[128];
    int ch = blockIdx.x, b = blockIdx.y, tid = threadIdx.x;
    a2[tid] = att2g[b*AA + tid];
    wf[tid] = wfa[tid];
    __syncthreads();
    int p0 = ch * 128;
    {
        int p_l = tid & 127, half = tid >> 7;
        const float* ap = att1T + ((size_t)b*AA + half*128)*PP + p0 + p_l;
        float s = half ? 0.f : bfa[0];
        #pragma unroll 4
        for (int a = 0; a < 128; ++a) {
            float x = ap[(size_t)a*PP] + a2[half*128 + a];
            float e2 = __expf(2.f * x);           // tanh(x) = 1 - 2/(e^2x+1)
            s += wf[half*128 + a] * (1.f - 2.f/(e2 + 1.f));
        }
        ps[half][p_l] = s;
    }
    __syncthreads();
    if (tid < 128) {
        float e = __expf(ps[0][tid] + ps[1][tid]);
        es[tid] = e;
        ws_e[((size_t)b*TT + t)*PP + p0 + tid] = e;  // unnormalized; f1_norm fixes later
    }
    __syncthreads();
    if (tid < 64) {
        float z = es[tid] + es[tid + 64];
        for (int o = 32; o > 0; o >>= 1) z += __shfl_down(z, o, 64);
        if (tid == 0) Zpart[b*4 + ch] = z;
    }
    // partial ctx: thread per channel c
    float acc = 0.f;
    const float4* ep = (const float4*)(encf + ((size_t)b*ENC + tid)*PP + p0);
    for (int k = 0; k < 32; ++k) {
        float4 v = ep[k];
        acc += es[k*4]*v.x + es[k*4+1]*v.y + es[k*4+2]*v.z + es[k*4+3]*v.w;
    }
    ctxU[(b*4 + ch)*ENC + tid] = acc;
}

// LSTM layer 0: x = [emb_t | ctx], K = 512 (+256 recurrent)
__global__ void s2_lstm0(const float* __restrict__ Wih0, const float* __restrict__ Whh0,
                         const float* __restrict__ bih0, const float* __restrict__ bhh0,
                         const float* __restrict__ emb, const int* __restrict__ caps,
                         const float* __restrict__ ctxU, const float* __restrict__ Zpart,
                         const float* __restrict__ h0p, const float* __restrict__ c0p,
                         float* __restrict__ h0n, float* __restrict__ c0n, int t) {
    __shared__ float xt[8][776];    // [b_l][0:256 emb | 256:512 ctx | 512:768 h0], pad 8
    __shared__ float gsm[8][4][9];
    __shared__ float zr[8];
    __shared__ int cps[8];
    int j0 = blockIdx.x * 8, b0 = blockIdx.y * 8, tid = threadIdx.x;
    if (tid < 8) {
        int b = b0 + tid;
        zr[tid] = 1.f / (Zpart[b*4] + Zpart[b*4+1] + Zpart[b*4+2] + Zpart[b*4+3]);
        cps[tid] = caps[b*TT + t];
    }
    __syncthreads();
    for (int i = tid; i < 8*768; i += 256) {
        int bl = i / 768, k = i - bl*768; int b = b0 + bl;
        float v;
        if (k < 256)      v = emb[(size_t)cps[bl]*EE + k];
        else if (k < 512) { int c = k - 256;
            v = (ctxU[(b*4)*ENC + c] + ctxU[(b*4+1)*ENC + c] +
                 ctxU[(b*4+2)*ENC + c] + ctxU[(b*4+3)*ENC + c]) * zr[bl]; }
        else              v = h0p[b*HD + k - 512];
        xt[bl][k] = v;
    }
    __syncthreads();
    int b_l = tid & 7, gate = (tid >> 3) & 3, j_l = tid >> 5;
    int g = gate*HD + j0 + j_l;
    float accA = bih0[g] + bhh0[g], accB = 0.f;
    const float4* wi = (const float4*)(Wih0 + (size_t)g*512);
    const float4* xb = (const float4*)xt[b_l];
    #pragma unroll 4
    for (int k = 0; k < 128; k += 2) {
        float4 w0 = wi[k],   x0 = xb[k];
        float4 w1 = wi[k+1], x1 = xb[k+1];
        accA += w0.x*x0.x + w0.y*x0.y + w0.z*x0.z + w0.w*x0.w;
        accB += w1.x*x1.x + w1.y*x1.y + w1.z*x1.z + w1.w*x1.w;
    }
    const float4* wh = (const float4*)(Whh0 + (size_t)g*HD);
    const float4* xh = (const float4*)(xt[b_l] + 512);
    #pragma unroll 4
    for (int k = 0; k < 64; k += 2) {
        float4 w0 = wh[k],   x0 = xh[k];
        float4 w1 = wh[k+1], x1 = xh[k+1];
        accA += w0.x*x0.x + w0.y*x0.y + w0.z*x0.z + w0.w*x0.w;
        accB += w1.x*x1.x + w1.y*x1.y + w1.z*x1.z + w1.w*x1.w;
    }
    gsm[j_l][gate][b_l] = accA + accB;
    __syncthreads();
    if (tid < 64) {
        int jl = tid >> 3, bl = tid & 7; int b = b0 + bl, j = j0 + jl;
        float gi = gsm[jl][0][bl], gf = gsm[jl][1][bl], gg = gsm[jl][2][bl], go = gsm[jl][3][bl];
        float si = 1.f/(1.f + __expf(-gi)), sf = 1.f/(1.f + __expf(-gf)), so = 1.f/(1.f + __expf(-go));
        float c2 = sf * c0p[b*HD + j] + si * tanhf(gg);
        c0n[b*HD + j] = c2;
        h0n[b*HD + j] = so * tanhf(c2);
    }
}

// LSTM layer 1: x = h0n, recurrent h1prev; writes h1 into H1all[t]
__global__ void s3_lstm1(const float* __restrict__ Wih1, const float* __restrict__ Whh1,
                         const float* __restrict__ bih1, const float* __restrict__ bhh1,
                         const float* __restrict__ h0n, const float* __restrict__ h1p,
                         const float* __restrict__ c1p,
                         float* __restrict__ h1out, float* __restrict__ c1n) {
    __shared__ float xt[8][520];    // [b_l][0:256 h0n | 256:512 h1prev], pad 8
    __shared__ float gsm[8][4][9];
    int j0 = blockIdx.x * 8, b0 = blockIdx.y * 8, tid = threadIdx.x;
    for (int i = tid; i < 8*512; i += 256) {
        int bl = i >> 9, k = i & 511; int b = b0 + bl;
        xt[bl][k] = (k < 256) ? h0n[b*HD + k] : h1p[b*HD + k - 256];
    }
    __syncthreads();
    int b_l = tid & 7, gate = (tid >> 3) & 3, j_l = tid >> 5;
    int g = gate*HD + j0 + j_l;
    float accA = bih1[g] + bhh1[g], accB = 0.f;
    const float4* wi = (const float4*)(Wih1 + (size_t)g*HD);
    const float4* xb = (const float4*)xt[b_l];
    #pragma unroll 4
    for (int k = 0; k < 64; k += 2) {
        float4 w0 = wi[k],   x0 = xb[k];
        float4 w1 = wi[k+1], x1 = xb[k+1];
        accA += w0.x*x0.x + w0.y*x0.y + w0.z*x0.z + w0.w*x0.w;
        accB += w1.x*x1.x + w1.y*x1.y + w1.z*x1.z + w1.w*x1.w;
    }
    const float4* wh = (const float4*)(Whh1 + (size_t)g*HD);
    const float4* xh = (const float4*)(xt[b_l] + 256);
    #pragma unroll 4
    for (int k = 0; k < 64; k += 2) {
        float4 w0 = wh[k],   x0 = xh[k];
        float4 w1 = wh[k+1], x1 = xh[k+1];
        accA += w0.x*x0.x + w0.y*x0.y + w0.z*x0.z + w0.w*x0.w;
        accB += w1.x*x1.x + w1.y*x1.y + w1.z*x1.z + w1.w*x1.w;
    }
    gsm[j_l][gate][b_l] = accA + accB;
    __syncthreads();
    if (tid < 64) {
        int jl = tid >> 3, bl = tid & 7; int b = b0 + bl, j = j0 + jl;
        float gi = gsm[jl][0][bl], gf = gsm[jl][1][bl], gg = gsm[jl][2][bl], go = gsm[jl][3][bl];
        float si = 1.f/(1.f + __expf(-gi)), sf = 1.f/(1.f + __expf(-gf)), so = 1.f/(1.f + __expf(-go));
        float c2 = sf * c1p[b*HD + j] + si * tanhf(gg);
        c1n[b*HD + j] = c2;
        h1out[b*HD + j] = so * tanhf(c2);
    }
}

// ---------------- finalization ----------------

// normalize attention weights in place: row /= sum(row)
__global__ void f1_norm(float* __restrict__ wsout) {
    int t = blockIdx.x, b = blockIdx.y, tid = threadIdx.x;
    float4* row = (float4*)(wsout + ((size_t)b*TT + t)*PP);
    float4 v = row[tid];
    float s = v.x + v.y + v.z + v.w;
    __shared__ float zz[2];
    for (int o = 32; o > 0; o >>= 1) s += __shfl_down(s, o, 64);
    if ((tid & 63) == 0) zz[tid >> 6] = s;
    __syncthreads();
    float r = 1.f / (zz[0] + zz[1]);
    v.x *= r; v.y *= r; v.z *= r; v.w *= r;
    row[tid] = v;
}

// out[b][t][v] = H1all[t][b]@W_out[v]^T + b_out[v]
__global__ __launch_bounds__(256)
void f2_out(const float* __restrict__ H1all, const float* __restrict__ Wout,
            const float* __restrict__ bout, float* __restrict__ out0) {
    __shared__ float Hs[16][260];
    int vt = blockIdx.x, rt = blockIdx.y, tid = threadIdx.x;
    int r0 = rt * 16;
    for (int i = tid; i < 16*256; i += 256) {
        int rl = i >> 8, c = i & 255;
        Hs[rl][c] = H1all[(size_t)(r0 + rl)*HD + c];
    }
    __syncthreads();
    int r_l = tid & 15, v_l = tid >> 4;
    int r = r0 + r_l; int tt = r >> 6, bb2 = r & 63;
    float* orow = out0 + ((size_t)bb2*TT + tt)*VV;
    const float4* hs = (const float4*)Hs[r_l];
    int vbase = vt*128 + v_l*8;
    for (int i = 0; i < 8; ++i) {
        int v = vbase + i;
        if (v >= VV) break;
        const float4* wr = (const float4*)(Wout + (size_t)v*HD);
        float accA = 0.f, accB = 0.f;
        #pragma unroll 4
        for (int k = 0; k < 64; k += 2) {
            float4 w0 = wr[k],   h0 = hs[k];
            float4 w1 = wr[k+1], h1 = hs[k+1];
            accA += w0.x*h0.x + w0.y*h0.y + w0.z*h0.z + w0.w*h0.w;
            accB += w1.x*h1.x + w1.y*h1.y + w1.z*h1.z + w1.w*h1.w;
        }
        orow[v] = accA + accB + bout[v];
    }
}

// ---------------- host ----------------

extern "C" void kernel_launch(void* const* d_in, const int* in_sizes, int n_in,
                              void* d_out, int out_size, void* d_ws, size_t ws_size,
                              hipStream_t stream) {
    const float* enc    = (const float*)d_in[0];
    const int*   caps   = (const int*)  d_in[1];
    const float* emb    = (const float*)d_in[2];
    const float* Wae    = (const float*)d_in[3];
    const float* bae    = (const float*)d_in[4];
    const float* Wad    = (const float*)d_in[5];
    const float* bad    = (const float*)d_in[6];
    const float* Wfa    = (const float*)d_in[7];
    const float* bfa    = (const float*)d_in[8];
    const float* Winith = (const float*)d_in[9];
    const float* binith = (const float*)d_in[10];
    const float* Winitc = (const float*)d_in[11];
    const float* binitc = (const float*)d_in[12];
    const float* Wih0   = (const float*)d_in[13];
    const float* Whh0   = (const float*)d_in[14];
    const float* bih0   = (const float*)d_in[15];
    const float* bhh0   = (const float*)d_in[16];
    const float* Wih1   = (const float*)d_in[17];
    const float* Whh1   = (const float*)d_in[18];
    const float* bih1   = (const float*)d_in[19];
    const float* bhh1   = (const float*)d_in[20];
    const float* Wout   = (const float*)d_in[21];
    const float* bout   = (const float*)d_in[22];

    // workspace layout (floats); total 12,796,160 floats = 51.2 MB
    float* ws     = (float*)d_ws;
    float* att1T  = ws;                      // 8,388,608
    float* H1all  = ws + 8388608;            // 4,194,304
    float* meanb  = ws + 12582912;           //    16,384
    float* h0b    = ws + 12599296;           //    32,768 (double buffer)
    float* c0b    = ws + 12632064;           //    32,768
    float* c1b    = ws + 12664832;           //    32,768
    float* h1init = ws + 12697600;           //    16,384
    float* att2g  = ws + 12713984;           //    16,384
    float* ctxU   = ws + 12730368;           //    65,536
    float* Zp     = ws + 12795904;           //       256

    float* out0  = (float*)d_out;
    float* wsout = out0 + (size_t)BB*TT*VV;  // attention-weight output region

    hipLaunchKernelGGL(k_mean,  dim3(BB),     dim3(256), 0, stream, enc, meanb);
    hipLaunchKernelGGL(k_init,  dim3(BB),     dim3(256), 0, stream, meanb, Winith, binith,
                       Winitc, binitc, h0b, c0b, h1init, c1b);
    hipLaunchKernelGGL(k_att1T, dim3(16, BB), dim3(512), 0, stream, enc, Wae, bae, att1T);

    for (int t = 0; t < TT; ++t) {
        const float* h1p = (t == 0) ? h1init : (H1all + (size_t)(t - 1)*BB*HD);
        int rp = t & 1, wp = rp ^ 1;
        hipLaunchKernelGGL(s0_att2, dim3(8, 4),  dim3(256), 0, stream, h1p, Wad, bad, att2g);
        hipLaunchKernelGGL(s1_score, dim3(4, BB), dim3(256), 0, stream, att1T, enc, att2g,
                           Wfa, bfa, wsout, ctxU, Zp, t);
        hipLaunchKernelGGL(s2_lstm0, dim3(32, 8), dim3(256), 0, stream, Wih0, Whh0, bih0, bhh0,
                           emb, caps, ctxU, Zp,
                           h0b + (size_t)rp*BB*HD, c0b + (size_t)rp*BB*HD,
                           h0b + (size_t)wp*BB*HD, c0b + (size_t)wp*BB*HD, t);
        hipLaunchKernelGGL(s3_lstm1, dim3(32, 8), dim3(256), 0, stream, Wih1, Whh1, bih1, bhh1,
                           h0b + (size_t)wp*BB*HD, h1p, c1b + (size_t)rp*BB*HD,
                           H1all + (size_t)t*BB*HD, c1b + (size_t)wp*BB*HD);
    }

    hipLaunchKernelGGL(f1_norm, dim3(TT, BB),  dim3(128), 0, stream, wsout);
    hipLaunchKernelGGL(f2_out,  dim3(16, 1024), dim3(256), 0, stream, H1all, Wout, bout, out0);
}